// Round 9
// baseline (3318.891 us; speedup 1.0000x reference)
//
#include <hip/hip_runtime.h>
#include <math.h>

#define B_   64
#define S_   3072
#define DIN  128
#define E_   64
#define H_   256
#define OUT_ 10
#define T_   1024
#define NG   32      // batch groups (2 batches each)
#define GB   2
#define NCH  8       // chunk-WGs per group; WG q owns h-indices [32q,32q+32)
#define NLINES 192   // stamped lines per group per parity: [q][cw][s] 8*4*6
#define SLOT 168     // padded k-half slice (168 % 32 = 8 -> bank-disjoint)
#define CW   4       // compute waves per WG
#define NTHR 448     // 7 waves: 4 compute + 3 helper

// workspace layout (bytes)
#define ACT_BYTES   (B_*E_*T_*4)              // actT[b][e][t] fp32 = 16 MB
#define HBUF_OFF    ACT_BYTES
#define HBUF_BYTES  (NG*2*NLINES*16)          // 192 KB of 16B lines
#define HFINAL_OFF  (HBUF_OFF + HBUF_BYTES)
#define HFINAL_BYTES (NG*GB*H_*4)             // 128 KB

typedef float f32x4 __attribute__((ext_vector_type(4)));

// IF-coherent access (cross-XCD safe, fence-free). Proven rounds 2/4/6/7.
__device__ __forceinline__ f32x4 coh_load_f32x4(const float* p) {
  f32x4 r;
  asm volatile("global_load_dwordx4 %0, %1, off sc0 sc1\n\ts_waitcnt vmcnt(0)"
               : "=v"(r) : "v"(p) : "memory");
  return r;
}
__device__ __forceinline__ void coh_store_f32x4(float* p, f32x4 v) {
  asm volatile("global_store_dwordx4 %0, %1, off sc0 sc1" :: "v"(p), "v"(v) : "memory");
}

__device__ __forceinline__ float fast_sigmoid(float x) {
  return __builtin_amdgcn_rcpf(1.0f + __expf(-x));
}
__device__ __forceinline__ float fast_tanh(float x) {
  return 2.0f * __builtin_amdgcn_rcpf(1.0f + __expf(-2.0f * x)) - 1.0f;
}

// ---------------------------------------------------------------------------
// Conv: normalize rows (L2 over D=128), conv1d k=3 stride=3, +bias, relu.
// ---------------------------------------------------------------------------
__global__ __launch_bounds__(512, 1) void conv_kernel(
    const float* __restrict__ in,     // [B][S][DIN]
    const float* __restrict__ cw,     // [E][DIN][3]
    const float* __restrict__ cb,     // [E]
    float* __restrict__ actT)         // [B][E][T]
{
  extern __shared__ float xs[];                 // 192 rows x 128 f, swizzled
  float4* xs4 = (float4*)xs;
  const int bid = blockIdx.x;
  const int b  = bid >> 4;
  const int tb = bid & 15;
  const int tid = threadIdx.x;

  const float4* gin = (const float4*)(in + (size_t)b*S_*DIN + (size_t)tb*192*DIN);
  #pragma unroll
  for (int i = 0; i < 12; ++i) {
    int f4 = tid + i*512;
    int r = f4 >> 5, dq = f4 & 31;
    xs4[r*32 + (dq ^ (r & 7))] = gin[f4];
  }
  __syncthreads();

  const int wv = tid >> 6, ln = tid & 63;
  for (int rr = 0; rr < 24; ++rr) {
    int r = wv*24 + rr;
    int u = r*32 + ((ln >> 1) ^ (r & 7));
    float2* p = (float2*)((char*)xs + (size_t)u*16 + (size_t)(ln & 1)*8);
    float2 v = *p;
    float s = v.x*v.x + v.y*v.y;
    #pragma unroll
    for (int off = 32; off >= 1; off >>= 1) s += __shfl_xor(s, off);
    float inv = 1.0f / fmaxf(sqrtf(s), 1e-12f);
    v.x *= inv; v.y *= inv;
    *p = v;
  }
  __syncthreads();

  const int eo = __builtin_amdgcn_readfirstlane(wv);
  float acc[8];
  #pragma unroll
  for (int j = 0; j < 8; ++j) acc[j] = cb[eo*8 + j];

  const int r0 = 3*ln, r1 = 3*ln + 1, r2 = 3*ln + 2;
  #pragma unroll 4
  for (int dq = 0; dq < 32; ++dq) {
    float4 x0 = xs4[r0*32 + (dq ^ (r0 & 7))];
    float4 x1 = xs4[r1*32 + (dq ^ (r1 & 7))];
    float4 x2 = xs4[r2*32 + (dq ^ (r2 & 7))];
    #pragma unroll
    for (int j = 0; j < 8; ++j) {
      const float* wp = cw + (size_t)(eo*8 + j)*(DIN*3) + dq*12;  // uniform
      acc[j] += x0.x*wp[0] + x1.x*wp[1] + x2.x*wp[2]
              + x0.y*wp[3] + x1.y*wp[4] + x2.y*wp[5]
              + x0.z*wp[6] + x1.z*wp[7] + x2.z*wp[8]
              + x0.w*wp[9] + x1.w*wp[10] + x2.w*wp[11];
    }
  }

  const int tg = tb*64 + ln;
  #pragma unroll
  for (int j = 0; j < 8; ++j) {
    int e = eo*8 + j;
    actT[(size_t)b*E_*T_ + (size_t)e*T_ + tg] = fmaxf(acc[j], 0.0f);
  }
}

// k index -> (khalf, slot) in the 0-conflict LDS layout
__device__ __forceinline__ void kmap(int hidx, int& kh, int& slot) {
  kh = (hidx < 160) ? 0 : 1;
  slot = (hidx < 160) ? hidx : hidx - 160;
}

// ---------------------------------------------------------------------------
// LSTM: 256 WGs = 32 groups x 8 chunks; group g = bid&31 (batches 2g,2g+1),
// chunk q = bid>>5 (h-indices [32q,32q+32)). 448 threads = 7 waves.
// COMPUTE waves 0-3 (256 thr): lane khalf=l&1, m=(l>>1)&3, octet o=l>>3;
//   hh = w*8+o; row = m*256+32q+hh. Each thread: half a gate row (40 f4 in
//   VGPR) x TWO batch accumulators (weights de-duplicated).
//   shfl_xor(1)=k-reduce, shfl_xor(2,4)=gate butterfly, update redundant
//   per octet; lanes l%8==0 pack 3 h-values/line and store stamped lines.
// HELPER waves 4-6 (192 thr): poll next step's stamped lines CONCURRENTLY
//   with compute (rl<168: one remote line each), scatter to next-parity LDS;
//   rl<128 also stage x(t+1). One __syncthreads per step joins both roles.
// Overwrite-safety: I see stamp t+2 from WG W => W's pollers finished all
// t+1 reads => parity slot reusable (same induction as r4/6/7).
// ---------------------------------------------------------------------------
__global__ __launch_bounds__(NTHR, 1) void lstm_kernel(
    const float* __restrict__ actT,   // [B][E][T]
    const float* __restrict__ w_ih,   // [1024][64]
    const float* __restrict__ w_hh,   // [1024][256]
    const float* __restrict__ b_ih,
    const float* __restrict__ b_hh,
    float* hbuf,                      // [NG][2][NLINES] f32x4 lines
    float* hfinal)                    // [NG][GB][H]
{
  __shared__ float sl[2][2][2][SLOT]; // [parity][batch][khalf][slot]

  const int bid = blockIdx.x;
  const int g = bid & 31;
  const int q = bid >> 5;
  const int tid = threadIdx.x;
  const int w = tid >> 6;
  const int l = tid & 63;
  const bool is_comp = (w < CW);

  const int khalf = l & 1;
  const int m     = (l >> 1) & 3;
  const int o     = l >> 3;                    // octet within wave
  const int hh    = w*8 + o;                   // 0..31 (compute waves)
  const int row   = m*256 + 32*q + hh;         // gate row in [0,1024)

  // weights -> VGPRs (compute waves only)
  float4 wv[40];
  float bias = 0.0f;
  if (is_comp) {
    if (khalf == 0) {
      const float4* ph = (const float4*)(w_hh + (size_t)row*H_);
      #pragma unroll
      for (int i = 0; i < 40; ++i) wv[i] = ph[i];
      bias = b_ih[row] + b_hh[row];
    } else {
      const float4* ph = (const float4*)(w_hh + (size_t)row*H_) + 40;
      #pragma unroll
      for (int i = 0; i < 24; ++i) wv[i] = ph[i];
      const float4* px = (const float4*)(w_ih + (size_t)row*E_);
      #pragma unroll
      for (int i = 0; i < 16; ++i) wv[24+i] = px[i];
    }
  }

  // zero all LDS slices (t=0 parity-0 h = 0)
  for (int i = tid; i < 2*2*2*SLOT; i += NTHR) ((float*)sl)[i] = 0.0f;

  // ---- store-lane roles (compute waves): lane l%8==0, line s=l>>3 (s<6)
  const int ss = l >> 3;
  const bool is_store = is_comp && ((l & 7) == 0) && (ss < 6);
  const int sline = q*24 + w*6 + ss;
  const int scnt = (ss == 5) ? 1 : 3;

  // ---- helper roles
  const int rl = (w - CW)*64 + l;              // 0..191 for helper waves
  const bool is_poll = (!is_comp) && (rl < 168);
  int pline = 0, pq = 0, pw = 0, ps2 = 0;
  if (is_poll) {
    int qq = rl / 24;
    pq = qq + (qq >= q ? 1 : 0);
    int rest = rl % 24;
    pw = rest / 6; ps2 = rest % 6;
    pline = pq*24 + pw*6 + ps2;
  }
  const int pcnt = (ps2 == 5) ? 1 : 3;
  const bool is_x = (!is_comp) && (rl < 128);
  const int xb = (rl >> 6) & 1, xe = rl & 63;
  const float* actp = actT + (size_t)((g*GB + xb)*E_ + xe)*T_;

  float* hb = hbuf + (size_t)g*(2*NLINES*4);   // floats

  // prologue: stage x(0)
  if (is_x) sl[0][xb][1][96 + xe] = actp[0];
  __syncthreads();

  float c0 = 0.0f, c1 = 0.0f;
  for (int t = 0; t < T_; ++t) {
    const int p = t & 1;

    if (is_comp) {
      // ---- GEMV over half-row, two batches (LDS broadcast reads)
      // bias enters BOTH batch accumulators (r8 bug: acc1 started at 0)
      float acc0 = bias, acc1 = bias;
      const float* hs0 = &sl[p][0][khalf][0];
      const float* hs1 = &sl[p][1][khalf][0];
      #pragma unroll
      for (int i = 0; i < 40; ++i) {
        float4 a4 = *(const float4*)(hs0 + i*4);
        float4 b4 = *(const float4*)(hs1 + i*4);
        acc0 += wv[i].x*a4.x + wv[i].y*a4.y + wv[i].z*a4.z + wv[i].w*a4.w;
        acc1 += wv[i].x*b4.x + wv[i].y*b4.y + wv[i].z*b4.z + wv[i].w*b4.w;
      }

      // k-half reduce + gate butterfly (lane bits: khalf=1, m=2|4)
      float k0 = acc0 + __shfl_xor(acc0, 1);
      float k1 = acc1 + __shfl_xor(acc1, 1);
      float a1 = __shfl_xor(k0, 2), a2 = __shfl_xor(k0, 4), a3 = __shfl_xor(a1, 4);
      float e1 = __shfl_xor(k1, 2), e2 = __shfl_xor(k1, 4), e3 = __shfl_xor(e1, 4);
      float gi0 = (m==0)?k0:(m==1)?a1:(m==2)?a2:a3;
      float gf0 = (m==0)?a1:(m==1)?k0:(m==2)?a3:a2;
      float gg0 = (m==0)?a2:(m==1)?a3:(m==2)?k0:a1;
      float go0 = (m==0)?a3:(m==1)?a2:(m==2)?a1:k0;
      float gi1 = (m==0)?k1:(m==1)?e1:(m==2)?e2:e3;
      float gf1 = (m==0)?e1:(m==1)?k1:(m==2)?e3:e2;
      float gg1 = (m==0)?e2:(m==1)?e3:(m==2)?k1:e1;
      float go1 = (m==0)?e3:(m==1)?e2:(m==2)?e1:k1;

      c0 = fast_sigmoid(gf0)*c0 + fast_sigmoid(gi0)*fast_tanh(gg0);
      float h0 = fast_sigmoid(go0)*fast_tanh(c0);
      c1 = fast_sigmoid(gf1)*c1 + fast_sigmoid(gi1)*fast_tanh(gg1);
      float h1 = fast_sigmoid(go1)*fast_tanh(c1);

      // gather 3 packed values (k = 3s+j; cell=k>>1, batch=k&1)
      float lv0, lv1, lv2;
      {
        int k0i = 3*ss, k1i = 3*ss + 1, k2i = 3*ss + 2;
        k1i = (k1i > 15) ? 15 : k1i;  k2i = (k2i > 15) ? 15 : k2i;
        int s0 = 8*((k0i >> 1) & 7), s1 = 8*((k1i >> 1) & 7), s2 = 8*((k2i >> 1) & 7);
        float t00 = __shfl(h0, s0, 64), t01 = __shfl(h1, s0, 64);
        float t10 = __shfl(h0, s1, 64), t11 = __shfl(h1, s1, 64);
        float t20 = __shfl(h0, s2, 64), t21 = __shfl(h1, s2, 64);
        lv0 = (k0i & 1) ? t01 : t00;
        lv1 = (k1i & 1) ? t11 : t10;
        lv2 = (k2i & 1) ? t21 : t20;
      }

      if (is_store) {
        f32x4 line;
        line[0] = lv0; line[1] = lv1; line[2] = lv2;
        line[3] = __int_as_float(t + 1);
        float* dp = hb + (size_t)((((t+1) & 1)*NLINES) + sline)*4;
        coh_store_f32x4(dp, line);
        // self-chunk bypass into next-parity LDS
        #pragma unroll
        for (int j = 0; j < 3; ++j) {
          if (j < scnt) {
            int k = 3*ss + j;
            int kh, slot; kmap(32*q + w*8 + (k >> 1), kh, slot);
            sl[p ^ 1][k & 1][kh][slot] = (j == 0) ? lv0 : (j == 1) ? lv1 : lv2;
          }
        }
        if (t == T_ - 1) {
          #pragma unroll
          for (int j = 0; j < 3; ++j) {
            if (j < scnt) {
              int k = 3*ss + j;
              hfinal[(size_t)g*GB*H_ + (size_t)(k & 1)*H_ + 32*q + w*8 + (k >> 1)]
                  = (j == 0) ? lv0 : (j == 1) ? lv1 : lv2;
            }
          }
        }
      }
    } else {
      // ---- helpers: stage x(t+1), poll next step's lines into sl[p^1]
      if (t < T_ - 1) {
        float xval = 0.0f;
        if (is_x) xval = actp[t + 1];
        if (is_poll) {
          const float* lp = hb + (size_t)(((t+1) & 1)*NLINES + pline)*4;
          f32x4 v = coh_load_f32x4(lp);
          while (__float_as_int(v[3]) != t + 1) v = coh_load_f32x4(lp);
          #pragma unroll
          for (int j = 0; j < 3; ++j) {
            if (j < pcnt) {
              int k = 3*ps2 + j;
              int kh, slot; kmap(32*pq + pw*8 + (k >> 1), kh, slot);
              sl[p ^ 1][k & 1][kh][slot] = v[j];
            }
          }
        }
        if (is_x) sl[p ^ 1][xb][1][96 + xe] = xval;
      }
    }
    __syncthreads();
  }
}

// ---------------------------------------------------------------------------
// Head: out[b][o] = h_last[b] . lin_w[o] + lin_b[o]
// ---------------------------------------------------------------------------
__global__ void head_kernel(const float* __restrict__ hfinal,
                            const float* __restrict__ lw,
                            const float* __restrict__ lb,
                            float* __restrict__ out)
{
  int idx = blockIdx.x*blockDim.x + threadIdx.x;
  if (idx >= B_*OUT_) return;
  int b = idx / OUT_, o = idx % OUT_;
  int g = b >> 1, bl = b & 1;
  const float* h = hfinal + (size_t)g*GB*H_ + (size_t)bl*H_;
  const float* wv = lw + (size_t)o*H_;
  float s = lb[o];
  #pragma unroll 8
  for (int k = 0; k < H_; ++k) s += h[k]*wv[k];
  out[idx] = s;
}

extern "C" void kernel_launch(void* const* d_in, const int* in_sizes, int n_in,
                              void* d_out, int out_size, void* d_ws, size_t ws_size,
                              hipStream_t stream) {
  const float* inputs = (const float*)d_in[0];
  const float* conv_w = (const float*)d_in[3];
  const float* conv_b = (const float*)d_in[4];
  const float* w_ih   = (const float*)d_in[5];
  const float* w_hh   = (const float*)d_in[6];
  const float* b_ih   = (const float*)d_in[7];
  const float* b_hh   = (const float*)d_in[8];
  const float* lin_w  = (const float*)d_in[9];
  const float* lin_b  = (const float*)d_in[10];

  float* actT   = (float*)d_ws;
  float* hbuf   = (float*)((char*)d_ws + HBUF_OFF);
  float* hfinal = (float*)((char*)d_ws + HFINAL_OFF);

  // clear stamps each launch (graph-replay safe: stamps restart at 1)
  hipMemsetAsync(hbuf, 0, HBUF_BYTES, stream);
  hipLaunchKernelGGL(conv_kernel, dim3(B_*16), dim3(512), 192*128*4, stream,
                     inputs, conv_w, conv_b, actT);
  hipLaunchKernelGGL(lstm_kernel, dim3(NG*NCH), dim3(NTHR), 0, stream,
                     actT, w_ih, w_hh, b_ih, b_hh, hbuf, hfinal);
  hipLaunchKernelGGL(head_kernel, dim3(3), dim3(256), 0, stream,
                     hfinal, lin_w, lin_b, (float*)d_out);
}

// Round 11
// 2200.926 us; speedup vs baseline: 1.5080x; 1.5080x over previous
//
#include <hip/hip_runtime.h>
#include <math.h>

#define B_   64
#define S_   3072
#define DIN  128
#define E_   64
#define H_   256
#define OUT_ 10
#define T_   1024
#define NG   32      // batch groups (2 batches each)
#define GB   2
#define NCH  8       // chunk-WGs per group; WG q owns h-indices [32q,32q+32)
#define NLINES 192   // stamped lines per group per parity: [q][wave][s] 8*8*3
#define SLOT 168     // padded k-half slice (168 % 32 = 8 -> bank-disjoint)

// workspace layout (bytes)
#define ACT_BYTES   (B_*E_*T_*4)              // actT[b][e][t] fp32 = 16 MB
#define HBUF_OFF    ACT_BYTES
#define HBUF_BYTES  (NG*2*NLINES*16)          // 192 KB of 16B lines
#define HFINAL_OFF  (HBUF_OFF + HBUF_BYTES)
#define HFINAL_BYTES (NG*GB*H_*4)             // 64 KB

typedef float f32x4 __attribute__((ext_vector_type(4)));

// IF-coherent access (cross-XCD safe, fence-free). Proven rounds 2/4/6/7.
// NOTE: sc0-only ("XCD-local") exchange hangs — twice confirmed (r3, r10).
__device__ __forceinline__ f32x4 coh_load_f32x4(const float* p) {
  f32x4 r;
  asm volatile("global_load_dwordx4 %0, %1, off sc0 sc1\n\ts_waitcnt vmcnt(0)"
               : "=v"(r) : "v"(p) : "memory");
  return r;
}
__device__ __forceinline__ void coh_store_f32x4(float* p, f32x4 v) {
  asm volatile("global_store_dwordx4 %0, %1, off sc0 sc1" :: "v"(p), "v"(v) : "memory");
}

// step barrier: LDS-drain only. __syncthreads would drain vmcnt(0) too,
// putting every thread behind the slowest store-ack each step; here only
// store lanes self-drain their own stores.
__device__ __forceinline__ void step_barrier() {
  asm volatile("s_waitcnt lgkmcnt(0)" ::: "memory");
  __builtin_amdgcn_sched_barrier(0);
  __builtin_amdgcn_s_barrier();
}

__device__ __forceinline__ float fast_sigmoid(float x) {
  return __builtin_amdgcn_rcpf(1.0f + __expf(-x));
}
__device__ __forceinline__ float fast_tanh(float x) {
  return 2.0f * __builtin_amdgcn_rcpf(1.0f + __expf(-2.0f * x)) - 1.0f;
}

// ---------------------------------------------------------------------------
// Conv: normalize rows (L2 over D=128), conv1d k=3 stride=3, +bias, relu.
// ---------------------------------------------------------------------------
__global__ __launch_bounds__(512, 1) void conv_kernel(
    const float* __restrict__ in,     // [B][S][DIN]
    const float* __restrict__ cw,     // [E][DIN][3]
    const float* __restrict__ cb,     // [E]
    float* __restrict__ actT)         // [B][E][T]
{
  extern __shared__ float xs[];                 // 192 rows x 128 f, swizzled
  float4* xs4 = (float4*)xs;
  const int bid = blockIdx.x;
  const int b  = bid >> 4;
  const int tb = bid & 15;
  const int tid = threadIdx.x;

  const float4* gin = (const float4*)(in + (size_t)b*S_*DIN + (size_t)tb*192*DIN);
  #pragma unroll
  for (int i = 0; i < 12; ++i) {
    int f4 = tid + i*512;
    int r = f4 >> 5, dq = f4 & 31;
    xs4[r*32 + (dq ^ (r & 7))] = gin[f4];
  }
  __syncthreads();

  const int wv = tid >> 6, ln = tid & 63;
  for (int rr = 0; rr < 24; ++rr) {
    int r = wv*24 + rr;
    int u = r*32 + ((ln >> 1) ^ (r & 7));
    float2* p = (float2*)((char*)xs + (size_t)u*16 + (size_t)(ln & 1)*8);
    float2 v = *p;
    float s = v.x*v.x + v.y*v.y;
    #pragma unroll
    for (int off = 32; off >= 1; off >>= 1) s += __shfl_xor(s, off);
    float inv = 1.0f / fmaxf(sqrtf(s), 1e-12f);
    v.x *= inv; v.y *= inv;
    *p = v;
  }
  __syncthreads();

  const int eo = __builtin_amdgcn_readfirstlane(wv);
  float acc[8];
  #pragma unroll
  for (int j = 0; j < 8; ++j) acc[j] = cb[eo*8 + j];

  const int r0 = 3*ln, r1 = 3*ln + 1, r2 = 3*ln + 2;
  #pragma unroll 4
  for (int dq = 0; dq < 32; ++dq) {
    float4 x0 = xs4[r0*32 + (dq ^ (r0 & 7))];
    float4 x1 = xs4[r1*32 + (dq ^ (r1 & 7))];
    float4 x2 = xs4[r2*32 + (dq ^ (r2 & 7))];
    #pragma unroll
    for (int j = 0; j < 8; ++j) {
      const float* wp = cw + (size_t)(eo*8 + j)*(DIN*3) + dq*12;  // uniform
      acc[j] += x0.x*wp[0] + x1.x*wp[1] + x2.x*wp[2]
              + x0.y*wp[3] + x1.y*wp[4] + x2.y*wp[5]
              + x0.z*wp[6] + x1.z*wp[7] + x2.z*wp[8]
              + x0.w*wp[9] + x1.w*wp[10] + x2.w*wp[11];
    }
  }

  const int tg = tb*64 + ln;
  #pragma unroll
  for (int j = 0; j < 8; ++j) {
    int e = eo*8 + j;
    actT[(size_t)b*E_*T_ + (size_t)e*T_ + tg] = fmaxf(acc[j], 0.0f);
  }
}

// k index -> (khalf, slot) in the 0-conflict LDS layout
__device__ __forceinline__ void kmap(int hidx, int& kh, int& slot) {
  kh = (hidx < 160) ? 0 : 1;
  slot = (hidx < 160) ? hidx : hidx - 160;
}

// ---------------------------------------------------------------------------
// LSTM (r7 symmetric structure + lgkm-only barrier + poller/store split):
// 256 WGs = 32 groups x 8 chunks; group g = bid&31, chunk q = bid>>5.
// Lane: khalf=l&1, m=(l>>1)&3, octet o=l>>3. Wave: b=w&1, wh=w>>1.
// Thread = half a gate row (40 f4 in VGPR); shfl_xor(1)=k-reduce,
// shfl_xor(2,4)=gate butterfly; update redundant per octet; store lanes
// (l%24==0) pack 3 h/line, store stamped 16B lines, then self-drain
// vmcnt(0) (protects store-data regs). Pollers are non-store lanes of
// waves 0-2 (168 remote lines); own chunk bypasses global via LDS.
// ---------------------------------------------------------------------------
__global__ __launch_bounds__(512, 1) void lstm_kernel(
    const float* __restrict__ actT,   // [B][E][T]
    const float* __restrict__ w_ih,   // [1024][64]
    const float* __restrict__ w_hh,   // [1024][256]
    const float* __restrict__ b_ih,
    const float* __restrict__ b_hh,
    float* hbuf,                      // [NG][2][NLINES] f32x4 lines
    float* hfinal)                    // [NG][GB][H]
{
  __shared__ float sl[2][2][2][SLOT]; // [parity][batch][khalf][slot]

  const int bid = blockIdx.x;
  const int g = bid & 31;
  const int q = bid >> 5;
  const int tid = threadIdx.x;
  const int w = tid >> 6;
  const int l = tid & 63;

  const int khalf = l & 1;
  const int m     = (l >> 1) & 3;
  const int o     = l >> 3;                    // octet within wave
  const int b     = w & 1;
  const int wh    = w >> 1;
  const int hh    = wh*8 + o;                  // 0..31 within chunk
  const int row   = m*256 + 32*q + hh;         // gate row in [0,1024)

  // weights -> VGPRs: 40 f4 = half-row
  float4 wv[40];
  if (khalf == 0) {
    const float4* ph = (const float4*)(w_hh + (size_t)row*H_);
    #pragma unroll
    for (int i = 0; i < 40; ++i) wv[i] = ph[i];
  } else {
    const float4* ph = (const float4*)(w_hh + (size_t)row*H_) + 40;
    #pragma unroll
    for (int i = 0; i < 24; ++i) wv[i] = ph[i];
    const float4* px = (const float4*)(w_ih + (size_t)row*E_);
    #pragma unroll
    for (int i = 0; i < 16; ++i) wv[24+i] = px[i];
  }
  const float bias = (khalf == 0) ? (b_ih[row] + b_hh[row]) : 0.0f;

  // zero all LDS slices (t=0 parity-0 h = 0)
  for (int i = tid; i < 2*2*2*SLOT; i += 512) ((float*)sl)[i] = 0.0f;

  // ---- store-lane roles: l in {0,24,48}, slot ss=l/24
  const int ss = l / 24;
  const bool is_store = ((l % 24) == 0);
  const int sline = q*24 + w*3 + ss;
  const int shh0 = wh*8 + 3*ss;
  const int scnt = (ss == 2) ? 2 : 3;

  // ---- poller roles: non-store lanes of waves 0-2 (bijective rank 0..60)
  const bool lane_ok = ((l % 24) != 0);
  const int rank = l - 1 - (l >= 24) - (l >= 48);
  const int pi = w*61 + rank;
  const bool is_poll = (w < 3) && lane_ok && (pi < 168);
  int pline = 0, pb = 0, phh0 = 0, pcnt = 3;
  if (is_poll) {
    int qq = pi / 24;
    int pq = qq + (qq >= q ? 1 : 0);
    int rest = pi % 24;
    int pw = rest / 3, ps = rest % 3;
    pline = pq*24 + pw*3 + ps;
    pb = pw & 1;
    phh0 = 32*pq + (pw >> 1)*8 + 3*ps;
    pcnt = (ps == 2) ? 2 : 3;
  }

  // ---- x loader roles: tid in [384,512)
  const bool is_x = (tid >= 384);
  const int xi = tid - 384, xb = (xi >> 6) & 1, xe = xi & 63;
  const float* actp = actT + (size_t)((g*GB + xb)*E_ + xe)*T_;

  float* hb = hbuf + (size_t)g*(2*NLINES*4);   // floats

  // prologue: stage x(0)
  if (is_x) sl[0][xb][1][96 + xe] = actp[0];
  __syncthreads();

  float c = 0.0f;
  for (int t = 0; t < T_; ++t) {
    const int p = t & 1;

    float xval = 0.0f;
    if (is_x) xval = actp[t];

    // poll my remote line (frozen at stamp t until this WG passes barrier)
    if (t > 0 && is_poll) {
      const float* lp = hb + (size_t)(p*NLINES + pline)*4;
      f32x4 v = coh_load_f32x4(lp);
      while (__float_as_int(v[3]) != t) v = coh_load_f32x4(lp);
      #pragma unroll
      for (int j = 0; j < 3; ++j) {
        if (j < pcnt) {
          int kh, slot; kmap(phh0 + j, kh, slot);
          sl[p][pb][kh][slot] = v[j];
        }
      }
    }
    if (is_x) sl[p][xb][1][96 + xe] = xval;
    step_barrier();   // LDS drained; h/x ready (no vmcnt drain here)

    // half-row GEMV: 40 f4 broadcast LDS reads
    float acc = bias;
    {
      const float* hs = &sl[p][b][khalf][0];
      #pragma unroll
      for (int i = 0; i < 40; ++i) {
        float4 h4 = *(const float4*)(hs + i*4);
        acc += wv[i].x*h4.x + wv[i].y*h4.y + wv[i].z*h4.z + wv[i].w*h4.w;
      }
    }

    // k-half reduce + gate butterfly (lane bits: khalf=1, m=2|4)
    float ksum = acc + __shfl_xor(acc, 1);
    float x1 = __shfl_xor(ksum, 2);
    float x2 = __shfl_xor(ksum, 4);
    float x3 = __shfl_xor(x1, 4);
    float gi = (m==0)?ksum:(m==1)?x1 :(m==2)?x2 :x3;
    float gf = (m==0)?x1 :(m==1)?ksum:(m==2)?x3 :x2;
    float gg = (m==0)?x2 :(m==1)?x3 :(m==2)?ksum:x1;
    float go = (m==0)?x3 :(m==1)?x2 :(m==2)?x1 :ksum;

    float si = fast_sigmoid(gi);
    float sf = fast_sigmoid(gf);
    float so = fast_sigmoid(go);
    c = sf*c + si*fast_tanh(gg);
    float h = so*fast_tanh(c);

    // pack 3 octet-values into the store lane (wave-internal shfl)
    float v1 = __shfl(h, (l + 8) & 63, 64);
    float v2 = __shfl(h, (l + 16) & 63, 64);
    if (is_store) {
      f32x4 line;
      line[0] = h; line[1] = v1; line[2] = v2;
      line[3] = __int_as_float(t + 1);
      float* dp = hb + (size_t)((((t+1) & 1)*NLINES) + sline)*4;
      coh_store_f32x4(dp, line);
      // self-chunk bypass into next-parity LDS (safe: all waves completed
      // iter t-? — the single rendezvous barrier per step guarantees no
      // reader of sl[p^1] remains; readers sync on the next step_barrier)
      #pragma unroll
      for (int j = 0; j < 3; ++j) {
        if (j < scnt) {
          int kh, slot; kmap(32*q + shh0 + j, kh, slot);
          sl[p ^ 1][b][kh][slot] = (j == 0) ? h : (j == 1) ? v1 : v2;
        }
      }
      if (t == T_ - 1) {
        #pragma unroll
        for (int j = 0; j < 3; ++j)
          if (j < scnt)
            hfinal[(size_t)g*GB*H_ + (size_t)b*H_ + 32*q + shh0 + j]
                = (j == 0) ? h : (j == 1) ? v1 : v2;
      }
      // drain own stores only (store-data regs must not be reused earlier)
      asm volatile("s_waitcnt vmcnt(0)" ::: "memory");
    }
  }
}

// ---------------------------------------------------------------------------
// Head: out[b][o] = h_last[b] . lin_w[o] + lin_b[o]
// ---------------------------------------------------------------------------
__global__ void head_kernel(const float* __restrict__ hfinal,
                            const float* __restrict__ lw,
                            const float* __restrict__ lb,
                            float* __restrict__ out)
{
  int idx = blockIdx.x*blockDim.x + threadIdx.x;
  if (idx >= B_*OUT_) return;
  int b = idx / OUT_, o = idx % OUT_;
  int g = b >> 1, bl = b & 1;
  const float* h = hfinal + (size_t)g*GB*H_ + (size_t)bl*H_;
  const float* wv = lw + (size_t)o*H_;
  float s = lb[o];
  #pragma unroll 8
  for (int k = 0; k < H_; ++k) s += h[k]*wv[k];
  out[idx] = s;
}

extern "C" void kernel_launch(void* const* d_in, const int* in_sizes, int n_in,
                              void* d_out, int out_size, void* d_ws, size_t ws_size,
                              hipStream_t stream) {
  const float* inputs = (const float*)d_in[0];
  const float* conv_w = (const float*)d_in[3];
  const float* conv_b = (const float*)d_in[4];
  const float* w_ih   = (const float*)d_in[5];
  const float* w_hh   = (const float*)d_in[6];
  const float* b_ih   = (const float*)d_in[7];
  const float* b_hh   = (const float*)d_in[8];
  const float* lin_w  = (const float*)d_in[9];
  const float* lin_b  = (const float*)d_in[10];

  float* actT   = (float*)d_ws;
  float* hbuf   = (float*)((char*)d_ws + HBUF_OFF);
  float* hfinal = (float*)((char*)d_ws + HFINAL_OFF);

  // clear stamps each launch (graph-replay safe: stamps restart at 1)
  hipMemsetAsync(hbuf, 0, HBUF_BYTES, stream);
  hipLaunchKernelGGL(conv_kernel, dim3(B_*16), dim3(512), 192*128*4, stream,
                     inputs, conv_w, conv_b, actT);
  hipLaunchKernelGGL(lstm_kernel, dim3(NG*NCH), dim3(512), 0, stream,
                     actT, w_ih, w_hh, b_ih, b_hh, hbuf, hfinal);
  hipLaunchKernelGGL(head_kernel, dim3(3), dim3(256), 0, stream,
                     hfinal, lin_w, lin_b, (float*)d_out);
}